// Round 3
// baseline (4700.248 us; speedup 1.0000x reference)
//
#include <hip/hip_runtime.h>
#include <math.h>

#define BB 8
#define NN 4096
#define DD 1024
#define PP 16
#define KS 8           // k-split for e-step
#define KC (DD / KS)   // 128 k per chunk

static constexpr float DLOG2PI = 1881.9861160031696f; // 1024 * log(2*pi)
static constexpr float EPSC = 0.1f;

// W layout: Wmat[b][k][32] interleaved pairs: [j*2]=invS_j(k), [j*2+1]=mu_j(k)*invS_j(k)
// All Wmat/qq accesses in the hot kernels are wave-uniform -> scalar (s_load) path.

// ---------------------------------------------------------------------------
// k_init: build Wmat + cns[b][j] = log pi - 0.5*(d log2pi + sum log S + sum mu^2/S)
// grid (16 j, 8 b), 256 threads (4 d each)
// ---------------------------------------------------------------------------
__global__ __launch_bounds__(256) void k_init(const float* __restrict__ m,
                                              const float* __restrict__ V_,
                                              float* __restrict__ Wmat,
                                              float* __restrict__ cns)
{
    int j = blockIdx.x, b = blockIdx.y;
    int tid = threadIdx.x;
    __shared__ float red[512];
    int d0 = tid * 4;
    float4 m4 = *(const float4*)(m + j * DD + d0);
    float4 v4 = *(const float4*)(V_ + j * DD + d0);
    float mv[4] = {m4.x, m4.y, m4.z, m4.w};
    float vv[4] = {v4.x, v4.y, v4.z, v4.w};
    float* Wb = Wmat + (size_t)b * (DD * 32);
    float llog = 0.f, lmq = 0.f;
#pragma unroll
    for (int c = 0; c < 4; c++) {
        float V = EPSC * log1pf(expf(vv[c]));
        float inv = 1.0f / V;
        int d = d0 + c;
        Wb[d * 32 + j * 2] = inv;
        Wb[d * 32 + j * 2 + 1] = mv[c] * inv;
        llog += logf(V);
        lmq += mv[c] * mv[c] * inv;
    }
    red[tid] = llog; red[256 + tid] = lmq;
    __syncthreads();
    for (int s = 128; s > 0; s >>= 1) {
        if (tid < s) { red[tid] += red[tid + s]; red[256 + tid] += red[256 + tid + s]; }
        __syncthreads();
    }
    if (tid == 0)
        cns[b * PP + j] = logf(1.0f / 16.0f) - 0.5f * (DLOG2PI + red[0] + red[256]);
}

// ---------------------------------------------------------------------------
// k_estep: NO LDS. Thread owns one row, one 128-k chunk. W streams through
// SGPRs (uniform index). X read as whole 64B lines (4 x float4 per 16 k).
// grid (16 rowblk, 8 ks, 8 b) = 1024 blocks, 256 threads.
// writes epart[ks][b][n][16] = -0.5*S1 + S2 partial.
// ---------------------------------------------------------------------------
__global__ __launch_bounds__(256) void k_estep(const float* __restrict__ X,
                                               const float* __restrict__ Wmat,
                                               float* __restrict__ epart)
{
    int rb = blockIdx.x, ks = blockIdx.y, b = blockIdx.z;
    int tid = threadIdx.x;
    int n = rb * 256 + tid;
    const float* xp = X + ((size_t)b * NN + n) * DD + ks * KC;
    const float* wp = Wmat + (size_t)b * (DD * 32) + (size_t)(ks * KC) * 32;
    float acc1[16] = {0,0,0,0,0,0,0,0,0,0,0,0,0,0,0,0};
    float acc2[16] = {0,0,0,0,0,0,0,0,0,0,0,0,0,0,0,0};
#pragma unroll 1
    for (int kk = 0; kk < KC; kk += 16) {
        float4 xv[4];
#pragma unroll
        for (int u = 0; u < 4; u++) xv[u] = *(const float4*)(xp + kk + u * 4);
        const float* w = wp + (size_t)kk * 32;
#pragma unroll
        for (int u = 0; u < 4; u++) {
            float xs[4] = {xv[u].x, xv[u].y, xv[u].z, xv[u].w};
#pragma unroll
            for (int c = 0; c < 4; c++) {
                float xvv = xs[c];
                float xq = xvv * xvv;
                const float* wk = w + (u * 4 + c) * 32;   // wave-uniform -> s_load
#pragma unroll
                for (int j = 0; j < 16; j++) {
                    acc1[j] = fmaf(xq,  wk[2 * j],     acc1[j]);
                    acc2[j] = fmaf(xvv, wk[2 * j + 1], acc2[j]);
                }
            }
        }
    }
    float* ep = epart + (((size_t)ks * BB + b) * NN + n) * PP;
#pragma unroll
    for (int q = 0; q < 4; q++) {
        float4 v = make_float4(-0.5f * acc1[q * 4 + 0] + acc2[q * 4 + 0],
                               -0.5f * acc1[q * 4 + 1] + acc2[q * 4 + 1],
                               -0.5f * acc1[q * 4 + 2] + acc2[q * 4 + 2],
                               -0.5f * acc1[q * 4 + 3] + acc2[q * 4 + 3]);
        *(float4*)(ep + q * 4) = v;
    }
}

// ---------------------------------------------------------------------------
// k_ereduce: sum KS k-partials + cns, softmax over 16 j, * mask -> qq
// grid (32 chunks of 128 rows, 8 b), 128 threads (1 row each)
// ---------------------------------------------------------------------------
__global__ __launch_bounds__(128) void k_ereduce(const float* __restrict__ epart,
                                                 const float* __restrict__ mask,
                                                 const float* __restrict__ cns,
                                                 float* __restrict__ qq)
{
    int chunk = blockIdx.x, b = blockIdx.y;
    int tid = threadIdx.x;
    int n = chunk * 128 + tid;
    __shared__ float cs[16];
    if (tid < 16) cs[tid] = cns[b * PP + tid];
    __syncthreads();
    float jl[16];
#pragma unroll
    for (int q = 0; q < 4; q++) {
        float4 v = *(const float4*)(epart + ((size_t)b * NN + n) * PP + q * 4);
        jl[q * 4 + 0] = v.x; jl[q * 4 + 1] = v.y; jl[q * 4 + 2] = v.z; jl[q * 4 + 3] = v.w;
    }
#pragma unroll
    for (int ks = 1; ks < KS; ks++) {
#pragma unroll
        for (int q = 0; q < 4; q++) {
            float4 v = *(const float4*)(epart + (((size_t)ks * BB + b) * NN + n) * PP + q * 4);
            jl[q * 4 + 0] += v.x; jl[q * 4 + 1] += v.y; jl[q * 4 + 2] += v.z; jl[q * 4 + 3] += v.w;
        }
    }
    float mx = -3.4e38f;
#pragma unroll
    for (int j = 0; j < 16; j++) { jl[j] += cs[j]; mx = fmaxf(mx, jl[j]); }
    float sum = 0.f;
#pragma unroll
    for (int j = 0; j < 16; j++) { jl[j] = expf(jl[j] - mx); sum += jl[j]; }
    float r = mask[(size_t)b * NN + n] / sum;
    float* qo = qq + ((size_t)b * NN + n) * PP;
#pragma unroll
    for (int q = 0; q < 4; q++)
        *(float4*)(qo + q * 4) = make_float4(jl[q * 4 + 0] * r, jl[q * 4 + 1] * r,
                                             jl[q * 4 + 2] * r, jl[q * 4 + 3] * r);
}

// ---------------------------------------------------------------------------
// k_mstep: NO LDS in hot loop. Block of 512 covers all 1024 cols x 2 n-phases.
// qq row is wave-uniform -> s_load_dwordx16. 128 accs/thread. Cross-phase
// reduce via padded LDS, then one partial per block.
// grid (32 nq of 128 rows, 8 b) = 256 blocks.
// ---------------------------------------------------------------------------
__global__ __launch_bounds__(512) void k_mstep(const float* __restrict__ X,
                                               const float* __restrict__ qq,
                                               float* __restrict__ wxp,
                                               float* __restrict__ wxxp)
{
    int nq = blockIdx.x, b = blockIdx.y;
    int tid = threadIdx.x;
    int cg = tid & 255;      // col group: 4 cols
    int ph = tid >> 8;       // 0/1 (wave-uniform: waves are 64-aligned)
    int col0 = cg * 4;
    const float* Xb = X + (size_t)b * NN * DD;
    const float* qb = qq + (size_t)b * NN * PP;
    float aw[16][4] = {};
    float ax[16][4] = {};
#pragma unroll 2
    for (int i = 0; i < 64; i++) {
        int n = nq * 128 + i * 2 + ph;
        float4 x = *(const float4*)(Xb + (size_t)n * DD + col0);
        const float* q = qb + (size_t)n * PP;   // wave-uniform -> s_load
        float x2x = x.x * x.x, x2y = x.y * x.y, x2z = x.z * x.z, x2w = x.w * x.w;
#pragma unroll
        for (int j = 0; j < 16; j++) {
            float qj = q[j];
            aw[j][0] = fmaf(qj, x.x, aw[j][0]);
            aw[j][1] = fmaf(qj, x.y, aw[j][1]);
            aw[j][2] = fmaf(qj, x.z, aw[j][2]);
            aw[j][3] = fmaf(qj, x.w, aw[j][3]);
            ax[j][0] = fmaf(qj, x2x, ax[j][0]);
            ax[j][1] = fmaf(qj, x2y, ax[j][1]);
            ax[j][2] = fmaf(qj, x2z, ax[j][2]);
            ax[j][3] = fmaf(qj, x2w, ax[j][3]);
        }
    }
    // cross-phase reduction: 4 passes through 33.8 KB padded LDS
    __shared__ float red[256 * 33];
#pragma unroll 1
    for (int pass = 0; pass < 4; pass++) {
        int jb = (pass & 1) * 8;
        __syncthreads();
        if (ph == 1) {
#pragma unroll
            for (int jj = 0; jj < 8; jj++) {
                const float (*src)[4] = (pass < 2) ? aw : ax;
                *(float4*)(&red[cg * 33 + jj * 4]) =
                    make_float4(src[jb + jj][0], src[jb + jj][1],
                                src[jb + jj][2], src[jb + jj][3]);
            }
        }
        __syncthreads();
        if (ph == 0) {
            float* dst = (pass < 2) ? wxp : wxxp;
#pragma unroll
            for (int jj = 0; jj < 8; jj++) {
                const float (*src)[4] = (pass < 2) ? aw : ax;
                float4 o = *(float4*)(&red[cg * 33 + jj * 4]);
                o.x += src[jb + jj][0];
                o.y += src[jb + jj][1];
                o.z += src[jb + jj][2];
                o.w += src[jb + jj][3];
                *(float4*)(dst + (((size_t)b * 32 + nq) * PP + jb + jj) * DD + col0) = o;
            }
        }
    }
}

// ---------------------------------------------------------------------------
// k_finalize: reduce 32 partials -> pi, mu, Sigma (d_out) and next-iter W, cns.
// grid (16 j, 8 b), 256 threads (4 d each).
// ---------------------------------------------------------------------------
__global__ __launch_bounds__(256) void k_finalize(const float* __restrict__ qq,
                                                  const float* __restrict__ wxp,
                                                  const float* __restrict__ wxxp,
                                                  const float* __restrict__ m,
                                                  const float* __restrict__ V_,
                                                  float* __restrict__ pi,
                                                  float* __restrict__ mu,
                                                  float* __restrict__ Sigma,
                                                  float* __restrict__ Wmat,
                                                  float* __restrict__ cns)
{
    int j = blockIdx.x, b = blockIdx.y;
    int tid = threadIdx.x;
    __shared__ float red[256 * 17 + 8]; // stride-17 to avoid bank conflicts
    __shared__ float wsr[16];
    __shared__ float sden;
    const float* qb = qq + (size_t)b * NN * PP;
    float ws[16] = {0,0,0,0,0,0,0,0,0,0,0,0,0,0,0,0};
    for (int i = 0; i < 16; i++) {
        int n = tid + i * 256;
        const float4 q0 = *(const float4*)(qb + (size_t)n * PP + 0);
        const float4 q1 = *(const float4*)(qb + (size_t)n * PP + 4);
        const float4 q2 = *(const float4*)(qb + (size_t)n * PP + 8);
        const float4 q3 = *(const float4*)(qb + (size_t)n * PP + 12);
        ws[0] += q0.x; ws[1] += q0.y; ws[2] += q0.z; ws[3] += q0.w;
        ws[4] += q1.x; ws[5] += q1.y; ws[6] += q1.z; ws[7] += q1.w;
        ws[8] += q2.x; ws[9] += q2.y; ws[10] += q2.z; ws[11] += q2.w;
        ws[12] += q3.x; ws[13] += q3.y; ws[14] += q3.z; ws[15] += q3.w;
    }
#pragma unroll
    for (int jj = 0; jj < 16; jj++) red[tid * 17 + jj] = ws[jj];
    __syncthreads();
    if (tid < 16) {
        float s = 0.f;
        for (int t = 0; t < 256; t++) s += red[t * 17 + tid];
        wsr[tid] = s + 1.0f; // + TAU
    }
    __syncthreads();
    if (tid == 0) {
        float dd = 0.f;
#pragma unroll
        for (int jj = 0; jj < 16; jj++) dd += wsr[jj];
        sden = dd;
    }
    __syncthreads();
    float rws = 1.0f / wsr[j];
    float pij = wsr[j] / sden;
    int d0 = tid * 4;
    float wxa[4] = {0, 0, 0, 0}, wxxa[4] = {0, 0, 0, 0};
#pragma unroll
    for (int g = 0; g < 32; g++) {
        const float4 a = *(const float4*)(wxp + (((size_t)b * 32 + g) * PP + j) * DD + d0);
        wxa[0] += a.x; wxa[1] += a.y; wxa[2] += a.z; wxa[3] += a.w;
        const float4 c2 = *(const float4*)(wxxp + (((size_t)b * 32 + g) * PP + j) * DD + d0);
        wxxa[0] += c2.x; wxxa[1] += c2.y; wxxa[2] += c2.z; wxxa[3] += c2.w;
    }
    float4 m4 = *(const float4*)(m + j * DD + d0);
    float4 v4 = *(const float4*)(V_ + j * DD + d0);
    float mvv[4] = {m4.x, m4.y, m4.z, m4.w};
    float vvv[4] = {v4.x, v4.y, v4.z, v4.w};
    float muo[4], sgo[4];
    float llog = 0.f, lmq = 0.f;
    float* Wb = Wmat + (size_t)b * (DD * 32);
#pragma unroll
    for (int c = 0; c < 4; c++) {
        float V = EPSC * log1pf(expf(vvv[c]));
        float muv = (wxa[c] + mvv[c]) * rws;                       // tau = 1
        float Sg = (wxxa[c] + V + mvv[c] * mvv[c]) * rws - muv * muv;
        float inv = 1.0f / Sg;
        muo[c] = muv; sgo[c] = Sg;
        int d = d0 + c;
        Wb[d * 32 + j * 2] = inv;
        Wb[d * 32 + j * 2 + 1] = muv * inv;
        llog += logf(Sg);
        lmq += muv * muv * inv;
    }
    *(float4*)(mu + ((size_t)b * PP + j) * DD + d0) = make_float4(muo[0], muo[1], muo[2], muo[3]);
    *(float4*)(Sigma + ((size_t)b * PP + j) * DD + d0) = make_float4(sgo[0], sgo[1], sgo[2], sgo[3]);
    red[tid] = llog; red[4096 + tid] = lmq;
    __syncthreads();
    for (int s = 128; s > 0; s >>= 1) {
        if (tid < s) { red[tid] += red[tid + s]; red[4096 + tid] += red[4096 + tid + s]; }
        __syncthreads();
    }
    if (tid == 0) {
        pi[b * PP + j] = pij;
        cns[b * PP + j] = logf(pij) - 0.5f * (DLOG2PI + red[0] + red[4096]);
    }
}

extern "C" void kernel_launch(void* const* d_in, const int* in_sizes, int n_in,
                              void* d_out, int out_size, void* d_ws, size_t ws_size,
                              hipStream_t stream)
{
    (void)in_sizes; (void)n_in; (void)out_size; (void)ws_size;
    const float* data = (const float*)d_in[0];
    const float* mask = (const float*)d_in[1];
    const float* m    = (const float*)d_in[2];
    const float* V_   = (const float*)d_in[3];

    float* out = (float*)d_out;
    float* pi  = out;                       // 128
    float* mu  = out + 128;                 // 131072
    float* Sg  = out + 128 + 131072;        // 131072
    float* qq  = out + 128 + 2 * 131072;    // 524288

    float* ws    = (float*)d_ws;
    float* Wmat  = ws;                        // 8*1024*32              = 262144
    float* cns   = ws + 262144;               // 128
    float* epart = ws + 262272;               // 8ks*8b*4096*16         = 4194304
    float* wxp   = ws + 262272 + 4194304;     // 8b*32nq*16*1024        = 4194304
    float* wxxp  = ws + 262272 + 2 * 4194304;

    k_init<<<dim3(16, 8), 256, 0, stream>>>(m, V_, Wmat, cns);
    for (int it = 0; it < 3; it++) {
        k_estep<<<dim3(16, KS, 8), 256, 0, stream>>>(data, Wmat, epart);
        k_ereduce<<<dim3(32, 8), 128, 0, stream>>>(epart, mask, cns, qq);
        k_mstep<<<dim3(32, 8), 512, 0, stream>>>(data, qq, wxp, wxxp);
        k_finalize<<<dim3(16, 8), 256, 0, stream>>>(qq, wxp, wxxp, m, V_, pi, mu, Sg, Wmat, cns);
    }
}

// Round 4
// 513.725 us; speedup vs baseline: 9.1493x; 9.1493x over previous
//
#include <hip/hip_runtime.h>
#include <math.h>

#define BB 8
#define NN 4096
#define DD 1024
#define PP 16
#define KS 8           // k-split for e-step
#define KC (DD / KS)   // 128 k per chunk

static constexpr float DLOG2PI = 1881.9861160031696f; // 1024 * log(2*pi)
static constexpr float EPSC = 0.1f;

// W layout: Wmat[b][k][32] interleaved pairs: [j*2]=invS_j(k), [j*2+1]=mu_j(k)*invS_j(k)
// All Wmat/qq accesses in the hot kernels are wave-uniform -> scalar (s_load) path.
// NOTE: never take a pointer/reference to the per-thread accumulator arrays —
// address-taking forces them to scratch (R3: VGPR=32, 6.5 GB spill traffic, 10x regression).

// ---------------------------------------------------------------------------
// k_init: build Wmat + cns[b][j] = log pi - 0.5*(d log2pi + sum log S + sum mu^2/S)
// grid (16 j, 8 b), 256 threads (4 d each)
// ---------------------------------------------------------------------------
__global__ __launch_bounds__(256) void k_init(const float* __restrict__ m,
                                              const float* __restrict__ V_,
                                              float* __restrict__ Wmat,
                                              float* __restrict__ cns)
{
    int j = blockIdx.x, b = blockIdx.y;
    int tid = threadIdx.x;
    __shared__ float red[512];
    int d0 = tid * 4;
    float4 m4 = *(const float4*)(m + j * DD + d0);
    float4 v4 = *(const float4*)(V_ + j * DD + d0);
    float mv[4] = {m4.x, m4.y, m4.z, m4.w};
    float vv[4] = {v4.x, v4.y, v4.z, v4.w};
    float* Wb = Wmat + (size_t)b * (DD * 32);
    float llog = 0.f, lmq = 0.f;
#pragma unroll
    for (int c = 0; c < 4; c++) {
        float V = EPSC * log1pf(expf(vv[c]));
        float inv = 1.0f / V;
        int d = d0 + c;
        Wb[d * 32 + j * 2] = inv;
        Wb[d * 32 + j * 2 + 1] = mv[c] * inv;
        llog += logf(V);
        lmq += mv[c] * mv[c] * inv;
    }
    red[tid] = llog; red[256 + tid] = lmq;
    __syncthreads();
    for (int s = 128; s > 0; s >>= 1) {
        if (tid < s) { red[tid] += red[tid + s]; red[256 + tid] += red[256 + tid + s]; }
        __syncthreads();
    }
    if (tid == 0)
        cns[b * PP + j] = logf(1.0f / 16.0f) - 0.5f * (DLOG2PI + red[0] + red[256]);
}

// ---------------------------------------------------------------------------
// k_estep: NO LDS. Thread owns one row, one 128-k chunk. W streams through
// SGPRs (uniform index). X read as whole 64B lines (4 x float4 per 16 k).
// grid (16 rowblk, 8 ks, 8 b) = 1024 blocks, 256 threads.
// writes epart[ks][b][n][16] = -0.5*S1 + S2 partial.
// ---------------------------------------------------------------------------
__global__ __launch_bounds__(256) void k_estep(const float* __restrict__ X,
                                               const float* __restrict__ Wmat,
                                               float* __restrict__ epart)
{
    int rb = blockIdx.x, ks = blockIdx.y, b = blockIdx.z;
    int tid = threadIdx.x;
    int n = rb * 256 + tid;
    const float* xp = X + ((size_t)b * NN + n) * DD + ks * KC;
    const float* wp = Wmat + (size_t)b * (DD * 32) + (size_t)(ks * KC) * 32;
    float acc1[16] = {0,0,0,0,0,0,0,0,0,0,0,0,0,0,0,0};
    float acc2[16] = {0,0,0,0,0,0,0,0,0,0,0,0,0,0,0,0};
#pragma unroll 1
    for (int kk = 0; kk < KC; kk += 16) {
        float4 xv[4];
#pragma unroll
        for (int u = 0; u < 4; u++) xv[u] = *(const float4*)(xp + kk + u * 4);
        const float* w = wp + (size_t)kk * 32;
#pragma unroll
        for (int u = 0; u < 4; u++) {
            float xs[4] = {xv[u].x, xv[u].y, xv[u].z, xv[u].w};
#pragma unroll
            for (int c = 0; c < 4; c++) {
                float xvv = xs[c];
                float xq = xvv * xvv;
                const float* wk = w + (u * 4 + c) * 32;   // wave-uniform -> s_load
#pragma unroll
                for (int j = 0; j < 16; j++) {
                    acc1[j] = fmaf(xq,  wk[2 * j],     acc1[j]);
                    acc2[j] = fmaf(xvv, wk[2 * j + 1], acc2[j]);
                }
            }
        }
    }
    float* ep = epart + (((size_t)ks * BB + b) * NN + n) * PP;
#pragma unroll
    for (int q = 0; q < 4; q++) {
        float4 v = make_float4(-0.5f * acc1[q * 4 + 0] + acc2[q * 4 + 0],
                               -0.5f * acc1[q * 4 + 1] + acc2[q * 4 + 1],
                               -0.5f * acc1[q * 4 + 2] + acc2[q * 4 + 2],
                               -0.5f * acc1[q * 4 + 3] + acc2[q * 4 + 3]);
        *(float4*)(ep + q * 4) = v;
    }
}

// ---------------------------------------------------------------------------
// k_ereduce: sum KS k-partials + cns, softmax over 16 j, * mask -> qq
// grid (32 chunks of 128 rows, 8 b), 128 threads (1 row each)
// ---------------------------------------------------------------------------
__global__ __launch_bounds__(128) void k_ereduce(const float* __restrict__ epart,
                                                 const float* __restrict__ mask,
                                                 const float* __restrict__ cns,
                                                 float* __restrict__ qq)
{
    int chunk = blockIdx.x, b = blockIdx.y;
    int tid = threadIdx.x;
    int n = chunk * 128 + tid;
    __shared__ float cs[16];
    if (tid < 16) cs[tid] = cns[b * PP + tid];
    __syncthreads();
    float jl[16];
#pragma unroll
    for (int q = 0; q < 4; q++) {
        float4 v = *(const float4*)(epart + ((size_t)b * NN + n) * PP + q * 4);
        jl[q * 4 + 0] = v.x; jl[q * 4 + 1] = v.y; jl[q * 4 + 2] = v.z; jl[q * 4 + 3] = v.w;
    }
#pragma unroll
    for (int ks = 1; ks < KS; ks++) {
#pragma unroll
        for (int q = 0; q < 4; q++) {
            float4 v = *(const float4*)(epart + (((size_t)ks * BB + b) * NN + n) * PP + q * 4);
            jl[q * 4 + 0] += v.x; jl[q * 4 + 1] += v.y; jl[q * 4 + 2] += v.z; jl[q * 4 + 3] += v.w;
        }
    }
    float mx = -3.4e38f;
#pragma unroll
    for (int j = 0; j < 16; j++) { jl[j] += cs[j]; mx = fmaxf(mx, jl[j]); }
    float sum = 0.f;
#pragma unroll
    for (int j = 0; j < 16; j++) { jl[j] = expf(jl[j] - mx); sum += jl[j]; }
    float r = mask[(size_t)b * NN + n] / sum;
    float* qo = qq + ((size_t)b * NN + n) * PP;
#pragma unroll
    for (int q = 0; q < 4; q++)
        *(float4*)(qo + q * 4) = make_float4(jl[q * 4 + 0] * r, jl[q * 4 + 1] * r,
                                             jl[q * 4 + 2] * r, jl[q * 4 + 3] * r);
}

// ---------------------------------------------------------------------------
// k_mstep: NO LDS in hot loop. Block of 512 covers all 1024 cols x 2 n-phases.
// qq row is wave-uniform -> s_load. 128 accs/thread (registers!). Cross-phase
// reduce via padded LDS in 4 statically-unrolled passes (no pointer-to-local).
// grid (32 nq of 128 rows, 8 b) = 256 blocks.
// ---------------------------------------------------------------------------
__global__ __launch_bounds__(512) void k_mstep(const float* __restrict__ X,
                                               const float* __restrict__ qq,
                                               float* __restrict__ wxp,
                                               float* __restrict__ wxxp)
{
    int nq = blockIdx.x, b = blockIdx.y;
    int tid = threadIdx.x;
    int cg = tid & 255;      // col group: 4 cols
    int ph = tid >> 8;       // 0/1 (wave-uniform: waves are 64-aligned)
    int col0 = cg * 4;
    const float* Xb = X + (size_t)b * NN * DD;
    const float* qb = qq + (size_t)b * NN * PP;
    float aw[16][4] = {};
    float ax[16][4] = {};
#pragma unroll 2
    for (int i = 0; i < 64; i++) {
        int n = nq * 128 + i * 2 + ph;
        float4 x = *(const float4*)(Xb + (size_t)n * DD + col0);
        const float* q = qb + (size_t)n * PP;   // wave-uniform -> s_load
        float x2x = x.x * x.x, x2y = x.y * x.y, x2z = x.z * x.z, x2w = x.w * x.w;
#pragma unroll
        for (int j = 0; j < 16; j++) {
            float qj = q[j];
            aw[j][0] = fmaf(qj, x.x, aw[j][0]);
            aw[j][1] = fmaf(qj, x.y, aw[j][1]);
            aw[j][2] = fmaf(qj, x.z, aw[j][2]);
            aw[j][3] = fmaf(qj, x.w, aw[j][3]);
            ax[j][0] = fmaf(qj, x2x, ax[j][0]);
            ax[j][1] = fmaf(qj, x2y, ax[j][1]);
            ax[j][2] = fmaf(qj, x2z, ax[j][2]);
            ax[j][3] = fmaf(qj, x2w, ax[j][3]);
        }
    }
    // cross-phase reduction: 4 statically-unrolled passes through padded LDS.
    // SRC is an array NAME (constant indices only) — keeps accs in VGPRs.
    __shared__ float red[256 * 33]; // 33.8 KB
#define MSTEP_PASS(SRC, JB, DST)                                               \
    __syncthreads();                                                           \
    if (ph == 1) {                                                             \
        _Pragma("unroll")                                                      \
        for (int jj = 0; jj < 8; jj++)                                         \
            *(float4*)(&red[cg * 33 + jj * 4]) =                               \
                make_float4(SRC[(JB) + jj][0], SRC[(JB) + jj][1],              \
                            SRC[(JB) + jj][2], SRC[(JB) + jj][3]);             \
    }                                                                          \
    __syncthreads();                                                           \
    if (ph == 0) {                                                             \
        _Pragma("unroll")                                                      \
        for (int jj = 0; jj < 8; jj++) {                                       \
            float4 o = *(float4*)(&red[cg * 33 + jj * 4]);                     \
            o.x += SRC[(JB) + jj][0];                                          \
            o.y += SRC[(JB) + jj][1];                                          \
            o.z += SRC[(JB) + jj][2];                                          \
            o.w += SRC[(JB) + jj][3];                                          \
            *(float4*)(DST + (((size_t)b * 32 + nq) * PP + (JB) + jj) * DD +   \
                       col0) = o;                                              \
        }                                                                      \
    }
    MSTEP_PASS(aw, 0, wxp)
    MSTEP_PASS(aw, 8, wxp)
    MSTEP_PASS(ax, 0, wxxp)
    MSTEP_PASS(ax, 8, wxxp)
#undef MSTEP_PASS
}

// ---------------------------------------------------------------------------
// k_finalize: reduce 32 partials -> pi, mu, Sigma (d_out) and next-iter W, cns.
// grid (16 j, 8 b), 256 threads (4 d each).
// ---------------------------------------------------------------------------
__global__ __launch_bounds__(256) void k_finalize(const float* __restrict__ qq,
                                                  const float* __restrict__ wxp,
                                                  const float* __restrict__ wxxp,
                                                  const float* __restrict__ m,
                                                  const float* __restrict__ V_,
                                                  float* __restrict__ pi,
                                                  float* __restrict__ mu,
                                                  float* __restrict__ Sigma,
                                                  float* __restrict__ Wmat,
                                                  float* __restrict__ cns)
{
    int j = blockIdx.x, b = blockIdx.y;
    int tid = threadIdx.x;
    __shared__ float red[256 * 17 + 8]; // stride-17 to avoid bank conflicts
    __shared__ float wsr[16];
    __shared__ float sden;
    const float* qb = qq + (size_t)b * NN * PP;
    float ws[16] = {0,0,0,0,0,0,0,0,0,0,0,0,0,0,0,0};
    for (int i = 0; i < 16; i++) {
        int n = tid + i * 256;
        const float4 q0 = *(const float4*)(qb + (size_t)n * PP + 0);
        const float4 q1 = *(const float4*)(qb + (size_t)n * PP + 4);
        const float4 q2 = *(const float4*)(qb + (size_t)n * PP + 8);
        const float4 q3 = *(const float4*)(qb + (size_t)n * PP + 12);
        ws[0] += q0.x; ws[1] += q0.y; ws[2] += q0.z; ws[3] += q0.w;
        ws[4] += q1.x; ws[5] += q1.y; ws[6] += q1.z; ws[7] += q1.w;
        ws[8] += q2.x; ws[9] += q2.y; ws[10] += q2.z; ws[11] += q2.w;
        ws[12] += q3.x; ws[13] += q3.y; ws[14] += q3.z; ws[15] += q3.w;
    }
#pragma unroll
    for (int jj = 0; jj < 16; jj++) red[tid * 17 + jj] = ws[jj];
    __syncthreads();
    if (tid < 16) {
        float s = 0.f;
        for (int t = 0; t < 256; t++) s += red[t * 17 + tid];
        wsr[tid] = s + 1.0f; // + TAU
    }
    __syncthreads();
    if (tid == 0) {
        float dd = 0.f;
#pragma unroll
        for (int jj = 0; jj < 16; jj++) dd += wsr[jj];
        sden = dd;
    }
    __syncthreads();
    float rws = 1.0f / wsr[j];
    float pij = wsr[j] / sden;
    int d0 = tid * 4;
    float wxa[4] = {0, 0, 0, 0}, wxxa[4] = {0, 0, 0, 0};
#pragma unroll
    for (int g = 0; g < 32; g++) {
        const float4 a = *(const float4*)(wxp + (((size_t)b * 32 + g) * PP + j) * DD + d0);
        wxa[0] += a.x; wxa[1] += a.y; wxa[2] += a.z; wxa[3] += a.w;
        const float4 c2 = *(const float4*)(wxxp + (((size_t)b * 32 + g) * PP + j) * DD + d0);
        wxxa[0] += c2.x; wxxa[1] += c2.y; wxxa[2] += c2.z; wxxa[3] += c2.w;
    }
    float4 m4 = *(const float4*)(m + j * DD + d0);
    float4 v4 = *(const float4*)(V_ + j * DD + d0);
    float mvv[4] = {m4.x, m4.y, m4.z, m4.w};
    float vvv[4] = {v4.x, v4.y, v4.z, v4.w};
    float muo[4], sgo[4];
    float llog = 0.f, lmq = 0.f;
    float* Wb = Wmat + (size_t)b * (DD * 32);
#pragma unroll
    for (int c = 0; c < 4; c++) {
        float V = EPSC * log1pf(expf(vvv[c]));
        float muv = (wxa[c] + mvv[c]) * rws;                       // tau = 1
        float Sg = (wxxa[c] + V + mvv[c] * mvv[c]) * rws - muv * muv;
        float inv = 1.0f / Sg;
        muo[c] = muv; sgo[c] = Sg;
        int d = d0 + c;
        Wb[d * 32 + j * 2] = inv;
        Wb[d * 32 + j * 2 + 1] = muv * inv;
        llog += logf(Sg);
        lmq += muv * muv * inv;
    }
    *(float4*)(mu + ((size_t)b * PP + j) * DD + d0) = make_float4(muo[0], muo[1], muo[2], muo[3]);
    *(float4*)(Sigma + ((size_t)b * PP + j) * DD + d0) = make_float4(sgo[0], sgo[1], sgo[2], sgo[3]);
    red[tid] = llog; red[4096 + tid] = lmq;
    __syncthreads();
    for (int s = 128; s > 0; s >>= 1) {
        if (tid < s) { red[tid] += red[tid + s]; red[4096 + tid] += red[4096 + tid + s]; }
        __syncthreads();
    }
    if (tid == 0) {
        pi[b * PP + j] = pij;
        cns[b * PP + j] = logf(pij) - 0.5f * (DLOG2PI + red[0] + red[4096]);
    }
}

extern "C" void kernel_launch(void* const* d_in, const int* in_sizes, int n_in,
                              void* d_out, int out_size, void* d_ws, size_t ws_size,
                              hipStream_t stream)
{
    (void)in_sizes; (void)n_in; (void)out_size; (void)ws_size;
    const float* data = (const float*)d_in[0];
    const float* mask = (const float*)d_in[1];
    const float* m    = (const float*)d_in[2];
    const float* V_   = (const float*)d_in[3];

    float* out = (float*)d_out;
    float* pi  = out;                       // 128
    float* mu  = out + 128;                 // 131072
    float* Sg  = out + 128 + 131072;        // 131072
    float* qq  = out + 128 + 2 * 131072;    // 524288

    float* ws    = (float*)d_ws;
    float* Wmat  = ws;                        // 8*1024*32              = 262144
    float* cns   = ws + 262144;               // 128
    float* epart = ws + 262272;               // 8ks*8b*4096*16         = 4194304
    float* wxp   = ws + 262272 + 4194304;     // 8b*32nq*16*1024        = 4194304
    float* wxxp  = ws + 262272 + 2 * 4194304;

    k_init<<<dim3(16, 8), 256, 0, stream>>>(m, V_, Wmat, cns);
    for (int it = 0; it < 3; it++) {
        k_estep<<<dim3(16, KS, 8), 256, 0, stream>>>(data, Wmat, epart);
        k_ereduce<<<dim3(32, 8), 128, 0, stream>>>(epart, mask, cns, qq);
        k_mstep<<<dim3(32, 8), 512, 0, stream>>>(data, qq, wxp, wxxp);
        k_finalize<<<dim3(16, 8), 256, 0, stream>>>(qq, wxp, wxxp, m, V_, pi, mu, Sg, Wmat, cns);
    }
}

// Round 5
// 510.892 us; speedup vs baseline: 9.2001x; 1.0055x over previous
//
#include <hip/hip_runtime.h>
#include <math.h>

#define BB 8
#define NN 4096
#define DD 1024
#define PP 16
#define KS 8           // k-split for e-step
#define KC (DD / KS)   // 128 k per chunk

static constexpr float DLOG2PI = 1881.9861160031696f; // 1024 * log(2*pi)
static constexpr float EPSC = 0.1f;

// W layout: Wmat[b][k][32] interleaved pairs: [j*2]=invS_j(k), [j*2+1]=mu_j(k)*invS_j(k)
// Wmat/qq accesses in hot kernels are wave-uniform -> scalar (s_load) path.
// NOTE (R3 lesson): never take a pointer/reference to per-thread accumulator
// arrays — address-taking forces them to scratch (VGPR=32 + GBs of spill).
// NOTE (R4 lesson): compiler allocates minimal VGPRs and exposes full memory
// latency; explicit ping-pong prefetch into constant-indexed register arrays
// is required to buy memory-level parallelism.

#define FELEM(v, c) ((c) == 0 ? (v).x : (c) == 1 ? (v).y : (c) == 2 ? (v).z : (v).w)

// ---------------------------------------------------------------------------
// k_init: build Wmat + cns[b][j] = log pi - 0.5*(d log2pi + sum log S + sum mu^2/S)
// grid (16 j, 8 b), 256 threads (4 d each)
// ---------------------------------------------------------------------------
__global__ __launch_bounds__(256) void k_init(const float* __restrict__ m,
                                              const float* __restrict__ V_,
                                              float* __restrict__ Wmat,
                                              float* __restrict__ cns)
{
    int j = blockIdx.x, b = blockIdx.y;
    int tid = threadIdx.x;
    __shared__ float red[512];
    int d0 = tid * 4;
    float4 m4 = *(const float4*)(m + j * DD + d0);
    float4 v4 = *(const float4*)(V_ + j * DD + d0);
    float mv[4] = {m4.x, m4.y, m4.z, m4.w};
    float vv[4] = {v4.x, v4.y, v4.z, v4.w};
    float* Wb = Wmat + (size_t)b * (DD * 32);
    float llog = 0.f, lmq = 0.f;
#pragma unroll
    for (int c = 0; c < 4; c++) {
        float V = EPSC * log1pf(expf(vv[c]));
        float inv = 1.0f / V;
        int d = d0 + c;
        Wb[d * 32 + j * 2] = inv;
        Wb[d * 32 + j * 2 + 1] = mv[c] * inv;
        llog += logf(V);
        lmq += mv[c] * mv[c] * inv;
    }
    red[tid] = llog; red[256 + tid] = lmq;
    __syncthreads();
    for (int s = 128; s > 0; s >>= 1) {
        if (tid < s) { red[tid] += red[tid + s]; red[256 + tid] += red[256 + tid + s]; }
        __syncthreads();
    }
    if (tid == 0)
        cns[b * PP + j] = logf(1.0f / 16.0f) - 0.5f * (DLOG2PI + red[0] + red[256]);
}

// ---------------------------------------------------------------------------
// k_estep: NO LDS. Thread owns TWO rows, one 128-k chunk. W streams through
// SGPRs; X tiles (16 k = one 64B line per row) explicitly double-buffered.
// grid (8 rowblk, 8 ks, 8 b) = 512 blocks, 256 threads.
// writes epart[ks][b][n][16] = -0.5*S1 + S2 partial.
// ---------------------------------------------------------------------------
__global__ __launch_bounds__(256) void k_estep(const float* __restrict__ X,
                                               const float* __restrict__ Wmat,
                                               float* __restrict__ epart)
{
    int rb = blockIdx.x, ks = blockIdx.y, b = blockIdx.z;
    int tid = threadIdx.x;
    int n0 = rb * 512 + tid * 2;   // rows n0, n0+1
    const float* xp0 = X + ((size_t)b * NN + n0) * DD + ks * KC;
    const float* xp1 = xp0 + DD;
    const float* wp = Wmat + (size_t)b * (DD * 32) + (size_t)(ks * KC) * 32;
    float a1[2][16] = {};
    float a2[2][16] = {};
    float4 cur[8], nxt[8];

#define ESTEP_LOAD(BUF, T)                                                     \
    _Pragma("unroll")                                                          \
    for (int u = 0; u < 4; u++) {                                              \
        BUF[u]     = *(const float4*)(xp0 + (T) * 16 + u * 4);                 \
        BUF[4 + u] = *(const float4*)(xp1 + (T) * 16 + u * 4);                 \
    }

#define ESTEP_COMPUTE(BUF, T)                                                  \
    _Pragma("unroll")                                                          \
    for (int u = 0; u < 4; u++) {                                              \
        _Pragma("unroll")                                                      \
        for (int c = 0; c < 4; c++) {                                          \
            const float* wk = wp + ((T) * 16 + u * 4 + c) * 32;                \
            float xv0 = FELEM(BUF[u], c),     xq0 = xv0 * xv0;                 \
            float xv1 = FELEM(BUF[4 + u], c), xq1 = xv1 * xv1;                 \
            _Pragma("unroll")                                                  \
            for (int j = 0; j < 16; j++) {                                     \
                a1[0][j] = fmaf(xq0, wk[2 * j],     a1[0][j]);                 \
                a2[0][j] = fmaf(xv0, wk[2 * j + 1], a2[0][j]);                 \
                a1[1][j] = fmaf(xq1, wk[2 * j],     a1[1][j]);                 \
                a2[1][j] = fmaf(xv1, wk[2 * j + 1], a2[1][j]);                 \
            }                                                                  \
        }                                                                      \
    }

    ESTEP_LOAD(cur, 0)
#pragma unroll 1
    for (int t = 0; t < 8; t += 2) {
        ESTEP_LOAD(nxt, t + 1)
        ESTEP_COMPUTE(cur, t)
        int t2 = (t + 2 < 8) ? t + 2 : 0;   // wrap: harmless reload, unused
        ESTEP_LOAD(cur, t2)
        ESTEP_COMPUTE(nxt, t + 1)
    }
#undef ESTEP_LOAD
#undef ESTEP_COMPUTE

    float* ep = epart + (((size_t)ks * BB + b) * NN + n0) * PP;
#pragma unroll
    for (int r = 0; r < 2; r++) {
#pragma unroll
        for (int q = 0; q < 4; q++) {
            float4 v = make_float4(-0.5f * a1[r][q * 4 + 0] + a2[r][q * 4 + 0],
                                   -0.5f * a1[r][q * 4 + 1] + a2[r][q * 4 + 1],
                                   -0.5f * a1[r][q * 4 + 2] + a2[r][q * 4 + 2],
                                   -0.5f * a1[r][q * 4 + 3] + a2[r][q * 4 + 3]);
            *(float4*)(ep + r * PP + q * 4) = v;
        }
    }
}

// ---------------------------------------------------------------------------
// k_ereduce: sum KS k-partials + cns, softmax over 16 j, * mask -> qq.
// Also emits per-block wsum partial wsum_p[b][chunk][16].
// grid (32 chunks of 128 rows, 8 b), 128 threads (1 row each)
// ---------------------------------------------------------------------------
__global__ __launch_bounds__(128) void k_ereduce(const float* __restrict__ epart,
                                                 const float* __restrict__ mask,
                                                 const float* __restrict__ cns,
                                                 float* __restrict__ qq,
                                                 float* __restrict__ wsum_p)
{
    int chunk = blockIdx.x, b = blockIdx.y;
    int tid = threadIdx.x;
    int n = chunk * 128 + tid;
    __shared__ float cs[16];
    __shared__ float red[128 * 17];
    if (tid < 16) cs[tid] = cns[b * PP + tid];
    __syncthreads();
    float jl[16];
#pragma unroll
    for (int q = 0; q < 4; q++) {
        float4 v = *(const float4*)(epart + ((size_t)b * NN + n) * PP + q * 4);
        jl[q * 4 + 0] = v.x; jl[q * 4 + 1] = v.y; jl[q * 4 + 2] = v.z; jl[q * 4 + 3] = v.w;
    }
#pragma unroll
    for (int ks = 1; ks < KS; ks++) {
#pragma unroll
        for (int q = 0; q < 4; q++) {
            float4 v = *(const float4*)(epart + (((size_t)ks * BB + b) * NN + n) * PP + q * 4);
            jl[q * 4 + 0] += v.x; jl[q * 4 + 1] += v.y; jl[q * 4 + 2] += v.z; jl[q * 4 + 3] += v.w;
        }
    }
    float mx = -3.4e38f;
#pragma unroll
    for (int j = 0; j < 16; j++) { jl[j] += cs[j]; mx = fmaxf(mx, jl[j]); }
    float sum = 0.f;
#pragma unroll
    for (int j = 0; j < 16; j++) { jl[j] = expf(jl[j] - mx); sum += jl[j]; }
    float r = mask[(size_t)b * NN + n] / sum;
    float* qo = qq + ((size_t)b * NN + n) * PP;
#pragma unroll
    for (int q = 0; q < 4; q++) {
        float4 v = make_float4(jl[q * 4 + 0] * r, jl[q * 4 + 1] * r,
                               jl[q * 4 + 2] * r, jl[q * 4 + 3] * r);
        *(float4*)(qo + q * 4) = v;
        red[tid * 17 + q * 4 + 0] = v.x;
        red[tid * 17 + q * 4 + 1] = v.y;
        red[tid * 17 + q * 4 + 2] = v.z;
        red[tid * 17 + q * 4 + 3] = v.w;
    }
    __syncthreads();
    if (tid < 16) {
        float s = 0.f;
#pragma unroll 8
        for (int t = 0; t < 128; t++) s += red[t * 17 + tid];
        wsum_p[((size_t)b * 32 + chunk) * 16 + tid] = s;
    }
}

// ---------------------------------------------------------------------------
// k_mstep: NO LDS in hot loop. Block of 512: all 1024 cols x 2 n-phases.
// qq row wave-uniform -> s_load. 128 accs/thread, explicit X double-buffer.
// Cross-phase reduce via padded LDS in 4 statically-unrolled passes.
// grid (32 nq of 128 rows, 8 b) = 256 blocks.
// ---------------------------------------------------------------------------
__global__ __launch_bounds__(512) void k_mstep(const float* __restrict__ X,
                                               const float* __restrict__ qq,
                                               float* __restrict__ wxp,
                                               float* __restrict__ wxxp)
{
    int nq = blockIdx.x, b = blockIdx.y;
    int tid = threadIdx.x;
    int cg = tid & 255;      // col group: 4 cols
    int ph = tid >> 8;       // 0/1 (wave-uniform)
    int col0 = cg * 4;
    const float* Xb = X + (size_t)b * NN * DD;
    const float* qb = qq + (size_t)b * NN * PP;
    int nbase = nq * 128 + ph;
    float aw[16][4] = {};
    float ax[16][4] = {};

#define MSTEP_FMA(XV, QP)                                                      \
    {                                                                          \
        float x2x = (XV).x * (XV).x, x2y = (XV).y * (XV).y;                    \
        float x2z = (XV).z * (XV).z, x2w = (XV).w * (XV).w;                    \
        _Pragma("unroll")                                                      \
        for (int j = 0; j < 16; j++) {                                         \
            float qj = (QP)[j];                                                \
            aw[j][0] = fmaf(qj, (XV).x, aw[j][0]);                             \
            aw[j][1] = fmaf(qj, (XV).y, aw[j][1]);                             \
            aw[j][2] = fmaf(qj, (XV).z, aw[j][2]);                             \
            aw[j][3] = fmaf(qj, (XV).w, aw[j][3]);                             \
            ax[j][0] = fmaf(qj, x2x, ax[j][0]);                                \
            ax[j][1] = fmaf(qj, x2y, ax[j][1]);                                \
            ax[j][2] = fmaf(qj, x2z, ax[j][2]);                                \
            ax[j][3] = fmaf(qj, x2w, ax[j][3]);                                \
        }                                                                      \
    }

    float4 xc = *(const float4*)(Xb + (size_t)nbase * DD + col0);
#pragma unroll 1
    for (int i = 0; i < 64; i += 2) {
        int na = nbase + i * 2;
        int nb_ = nbase + (i + 1) * 2;
        float4 xn = *(const float4*)(Xb + (size_t)nb_ * DD + col0);
        const float* q0 = qb + (size_t)na * PP;    // wave-uniform -> s_load
        MSTEP_FMA(xc, q0)
        int i2 = (i + 2 < 64) ? i + 2 : 0;         // wrap: harmless reload
        xc = *(const float4*)(Xb + (size_t)(nbase + i2 * 2) * DD + col0);
        const float* q1 = qb + (size_t)nb_ * PP;
        MSTEP_FMA(xn, q1)
    }
#undef MSTEP_FMA

    // cross-phase reduction: 4 statically-unrolled passes through padded LDS.
    __shared__ float red[256 * 33]; // 33.8 KB
#define MSTEP_PASS(SRC, JB, DST)                                               \
    __syncthreads();                                                           \
    if (ph == 1) {                                                             \
        _Pragma("unroll")                                                      \
        for (int jj = 0; jj < 8; jj++)                                         \
            *(float4*)(&red[cg * 33 + jj * 4]) =                               \
                make_float4(SRC[(JB) + jj][0], SRC[(JB) + jj][1],              \
                            SRC[(JB) + jj][2], SRC[(JB) + jj][3]);             \
    }                                                                          \
    __syncthreads();                                                           \
    if (ph == 0) {                                                             \
        _Pragma("unroll")                                                      \
        for (int jj = 0; jj < 8; jj++) {                                       \
            float4 o = *(float4*)(&red[cg * 33 + jj * 4]);                     \
            o.x += SRC[(JB) + jj][0];                                          \
            o.y += SRC[(JB) + jj][1];                                          \
            o.z += SRC[(JB) + jj][2];                                          \
            o.w += SRC[(JB) + jj][3];                                          \
            *(float4*)(DST + (((size_t)b * 32 + nq) * PP + (JB) + jj) * DD +   \
                       col0) = o;                                              \
        }                                                                      \
    }
    MSTEP_PASS(aw, 0, wxp)
    MSTEP_PASS(aw, 8, wxp)
    MSTEP_PASS(ax, 0, wxxp)
    MSTEP_PASS(ax, 8, wxxp)
#undef MSTEP_PASS
}

// ---------------------------------------------------------------------------
// k_finalize: wsum from wsum_p partials; reduce 32 wx/wxx partials -> pi, mu,
// Sigma (d_out) and next-iter W, cns. grid (16 j, 8 b), 256 threads.
// ---------------------------------------------------------------------------
__global__ __launch_bounds__(256) void k_finalize(const float* __restrict__ wsum_p,
                                                  const float* __restrict__ wxp,
                                                  const float* __restrict__ wxxp,
                                                  const float* __restrict__ m,
                                                  const float* __restrict__ V_,
                                                  float* __restrict__ pi,
                                                  float* __restrict__ mu,
                                                  float* __restrict__ Sigma,
                                                  float* __restrict__ Wmat,
                                                  float* __restrict__ cns)
{
    int j = blockIdx.x, b = blockIdx.y;
    int tid = threadIdx.x;
    __shared__ float red[512];
    __shared__ float redw[16 * 17];
    __shared__ float wsr[16];
    __shared__ float sden;
    // wsum: 256 threads = 16 j x 16 chunk-pairs
    {
        int j2 = tid & 15, c2 = tid >> 4;
        float s = wsum_p[((size_t)b * 32 + 2 * c2) * 16 + j2]
                + wsum_p[((size_t)b * 32 + 2 * c2 + 1) * 16 + j2];
        redw[c2 * 17 + j2] = s;
    }
    __syncthreads();
    if (tid < 16) {
        float s = 0.f;
#pragma unroll
        for (int c2 = 0; c2 < 16; c2++) s += redw[c2 * 17 + tid];
        wsr[tid] = s + 1.0f; // + TAU
    }
    __syncthreads();
    if (tid == 0) {
        float dd = 0.f;
#pragma unroll
        for (int jj = 0; jj < 16; jj++) dd += wsr[jj];
        sden = dd;
    }
    __syncthreads();
    float rws = 1.0f / wsr[j];
    float pij = wsr[j] / sden;
    int d0 = tid * 4;
    float wxa[4] = {0, 0, 0, 0}, wxxa[4] = {0, 0, 0, 0};
#pragma unroll
    for (int g = 0; g < 32; g++) {
        const float4 a = *(const float4*)(wxp + (((size_t)b * 32 + g) * PP + j) * DD + d0);
        wxa[0] += a.x; wxa[1] += a.y; wxa[2] += a.z; wxa[3] += a.w;
        const float4 c2 = *(const float4*)(wxxp + (((size_t)b * 32 + g) * PP + j) * DD + d0);
        wxxa[0] += c2.x; wxxa[1] += c2.y; wxxa[2] += c2.z; wxxa[3] += c2.w;
    }
    float4 m4 = *(const float4*)(m + j * DD + d0);
    float4 v4 = *(const float4*)(V_ + j * DD + d0);
    float mvv[4] = {m4.x, m4.y, m4.z, m4.w};
    float vvv[4] = {v4.x, v4.y, v4.z, v4.w};
    float muo[4], sgo[4];
    float llog = 0.f, lmq = 0.f;
    float* Wb = Wmat + (size_t)b * (DD * 32);
#pragma unroll
    for (int c = 0; c < 4; c++) {
        float V = EPSC * log1pf(expf(vvv[c]));
        float muv = (wxa[c] + mvv[c]) * rws;                       // tau = 1
        float Sg = (wxxa[c] + V + mvv[c] * mvv[c]) * rws - muv * muv;
        float inv = 1.0f / Sg;
        muo[c] = muv; sgo[c] = Sg;
        int d = d0 + c;
        Wb[d * 32 + j * 2] = inv;
        Wb[d * 32 + j * 2 + 1] = muv * inv;
        llog += logf(Sg);
        lmq += muv * muv * inv;
    }
    *(float4*)(mu + ((size_t)b * PP + j) * DD + d0) = make_float4(muo[0], muo[1], muo[2], muo[3]);
    *(float4*)(Sigma + ((size_t)b * PP + j) * DD + d0) = make_float4(sgo[0], sgo[1], sgo[2], sgo[3]);
    red[tid] = llog; red[256 + tid] = lmq;
    __syncthreads();
    for (int s = 128; s > 0; s >>= 1) {
        if (tid < s) { red[tid] += red[tid + s]; red[256 + tid] += red[256 + tid + s]; }
        __syncthreads();
    }
    if (tid == 0) {
        pi[b * PP + j] = pij;
        cns[b * PP + j] = logf(pij) - 0.5f * (DLOG2PI + red[0] + red[256]);
    }
}

extern "C" void kernel_launch(void* const* d_in, const int* in_sizes, int n_in,
                              void* d_out, int out_size, void* d_ws, size_t ws_size,
                              hipStream_t stream)
{
    (void)in_sizes; (void)n_in; (void)out_size; (void)ws_size;
    const float* data = (const float*)d_in[0];
    const float* mask = (const float*)d_in[1];
    const float* m    = (const float*)d_in[2];
    const float* V_   = (const float*)d_in[3];

    float* out = (float*)d_out;
    float* pi  = out;                       // 128
    float* mu  = out + 128;                 // 131072
    float* Sg  = out + 128 + 131072;        // 131072
    float* qq  = out + 128 + 2 * 131072;    // 524288

    float* ws     = (float*)d_ws;
    float* Wmat   = ws;                        // 8*1024*32              = 262144
    float* cns    = ws + 262144;               // 128
    float* epart  = ws + 262272;               // 8ks*8b*4096*16         = 4194304
    float* wxp    = ws + 262272 + 4194304;     // 8b*32nq*16*1024        = 4194304
    float* wxxp   = ws + 262272 + 2 * 4194304;
    float* wsum_p = ws + 262272 + 3 * 4194304; // 8b*32*16               = 4096

    k_init<<<dim3(16, 8), 256, 0, stream>>>(m, V_, Wmat, cns);
    for (int it = 0; it < 3; it++) {
        k_estep<<<dim3(8, KS, 8), 256, 0, stream>>>(data, Wmat, epart);
        k_ereduce<<<dim3(32, 8), 128, 0, stream>>>(epart, mask, cns, qq, wsum_p);
        k_mstep<<<dim3(32, 8), 512, 0, stream>>>(data, qq, wxp, wxxp);
        k_finalize<<<dim3(16, 8), 256, 0, stream>>>(wsum_p, wxp, wxxp, m, V_, pi, mu, Sg, Wmat, cns);
    }
}